// Round 13
// baseline (303.676 us; speedup 1.0000x reference)
//
#include <hip/hip_runtime.h>
#include <stdint.h>

typedef unsigned short u16;
typedef __attribute__((ext_vector_type(8))) __bf16 bf16x8;
typedef __attribute__((ext_vector_type(4))) float f32x4;
typedef __attribute__((ext_vector_type(8))) unsigned short ushort8;

__device__ __forceinline__ u16 f2bf(float f) {
  unsigned int u = __builtin_bit_cast(unsigned int, f);
  return (u16)((u + 0x7fffu + ((u >> 16) & 1u)) >> 16);
}

__device__ __forceinline__ float fexp2(float x) {
  float r;
  asm volatile("v_exp_f32 %0, %1" : "=v"(r) : "v"(x));
  return r;
}

__device__ __forceinline__ f32x4 mfma16(bf16x8 a, bf16x8 b, f32x4 c) {
  return __builtin_amdgcn_mfma_f32_16x16x32_bf16(a, b, c, 0, 0, 0);
}

__device__ __forceinline__ void gload_lds16(const void* g, void* l) {
  __builtin_amdgcn_global_load_lds((const __attribute__((address_space(1))) void*)g,
                                   (__attribute__((address_space(3))) void*)l,
                                   16, 0, 0);
}

#define KSCALE 0.18033688011112294f  /* 0.125 * log2(e) */

// ---------------- merged f32 -> bf16 convert (one launch) ----------------
__global__ void __launch_bounds__(256) cvt_all(
    const float* __restrict__ q, const float* __restrict__ w1,
    const float* __restrict__ w2, u16* __restrict__ qb,
    u16* __restrict__ w1b, u16* __restrict__ w2b) {
  int i = blockIdx.x * 256 + threadIdx.x;
  const float* src;
  u16* dst;
  int off;
  if (i < 4194304) {
    src = q; dst = qb; off = i;
  } else if (i < 4194304 + 786432) {
    src = w1; dst = w1b; off = i - 4194304;
  } else {
    src = w2; dst = w2b; off = i - 4980736;
  }
  float4 v = ((const float4*)src)[off];
  u16* d = dst + (size_t)off * 4;
  d[0] = f2bf(v.x); d[1] = f2bf(v.y); d[2] = f2bf(v.z); d[3] = f2bf(v.w);
}

// ================= 256x256 8-phase NT GEMM, 128x128 wave tile ============
// 4 waves (256 thr), wave tile 128x128 (acc[8][8]): FLOP per ds_read 1.5x
// r10's 128x64 -> LDS-read pipe no longer binds. r10's verified ledger with
// every stage slot = 2 gload_lds (VMW counts x2). 1 wave/SIMD; read-ahead
// ILP hides LDS latency.
#define LDV(p) (*(const bf16x8*)(p))
#define RD_LO(AS, C) { aL[0]=LDV(AS+aRow+(C)); aL[1]=LDV(AS+aRow+1024+(C)); \
                       aL[2]=LDV(AS+aRow+2048+(C)); aL[3]=LDV(AS+aRow+3072+(C)); }
#define RD_HI(AS, C) { aH[0]=LDV(AS+aRow+4096+(C)); aH[1]=LDV(AS+aRow+5120+(C)); \
                       aH[2]=LDV(AS+aRow+6144+(C)); aH[3]=LDV(AS+aRow+7168+(C)); }
#define RD_B(BS, R, C) { _Pragma("unroll") for (int ni=0;ni<8;++ni) \
                           R[ni]=LDV(BS+bRow+ni*1024+(C)); }
#define STA(DST, Q, T) { const u16* p_ = baseA + (size_t)((Q)*64)*K + (size_t)(T)*64; \
                         gload_lds16(p_, (DST)+(Q)*4096 + stDst); \
                         gload_lds16(p_ + 8*(size_t)K, (DST)+(Q)*4096 + stDst + 512); }
#define STB(DST, Q, T) { const u16* p_ = baseB + (size_t)((Q)*64)*K + (size_t)(T)*64; \
                         gload_lds16(p_, (DST)+(Q)*4096 + stDst); \
                         gload_lds16(p_ + 8*(size_t)K, (DST)+(Q)*4096 + stDst + 512); }
#define MM_LO(BB) { _Pragma("unroll") for (int mi=0;mi<4;++mi) \
                    _Pragma("unroll") for (int ni=0;ni<8;++ni) \
                      acc[mi][ni]=mfma16(aL[mi],(BB)[ni],acc[mi][ni]); }
#define MM_HI(BB) { _Pragma("unroll") for (int mi=0;mi<4;++mi) \
                    _Pragma("unroll") for (int ni=0;ni<8;++ni) \
                      acc[mi+4][ni]=mfma16(aH[mi],(BB)[ni],acc[mi+4][ni]); }
#define VMW(N) asm volatile("s_waitcnt vmcnt(" #N ")" ::: "memory")
#define BAR() __builtin_amdgcn_s_barrier()
#define PRIO1() __builtin_amdgcn_s_setprio(1)
#define PRIO0() __builtin_amdgcn_s_setprio(0)
#define MFMA_PH(MM, BB) { PRIO1(); MM(BB); PRIO0(); }

template <int MODE>
__global__ void __launch_bounds__(256, 1) gemm8p(
    const u16* __restrict__ A, const u16* __restrict__ B,
    const float* __restrict__ bias, void* __restrict__ Cout,
    u16* __restrict__ q_out, u16* __restrict__ k_out, u16* __restrict__ v_out,
    int M, int N, int K) {
  __shared__ alignas(16) u16 SH[65536];  // A:2x32KB, B:2x32KB; epilogue C-tile

  const int tid = threadIdx.x;
  const int w = tid >> 6, l = tid & 63;
  const int wm = w >> 1, wn = w & 1;
  const long bm = (long)blockIdx.x * 256;
  const long bn = (long)blockIdx.y * 256;
  const int NT = K >> 6;
  const int NIT = NT >> 1;

  // staging: quarter = 64 rows x 64 cols (8KB); thread does 2x16B.
  // chunkidx = w*128 + j*64 + l -> row = idx>>3 (j=1: +8), chunk = l&7.
  const int sr0 = (w * 128 + l) >> 3;
  const int scc = (((l & 7) ^ (sr0 & 7)) * 8);
  const u16* baseA = A + (bm + sr0) * (size_t)K + scc;
  const u16* baseB = B + (bn + sr0) * (size_t)K + scc;
  const int stDst = w * 1024;

  u16* const as0 = SH;
  u16* const as1 = SH + 16384;
  u16* const bs0 = SH + 32768;
  u16* const bs1 = SH + 49152;

  const int fr = l & 15, fkg = l >> 4;
  const int sw = (fr & 7) << 3;
  const int c0 = (fkg * 8) ^ sw;
  const int c1 = (32 + fkg * 8) ^ sw;
  const int aRow = (wm * 128 + fr) * 64;
  const int bRow = (wn * 128 + fr) * 64;

  f32x4 acc[8][8] = {};
  bf16x8 aL[4], aH[4], b0[8], b1[8];

  // prologue: t0 (8 quarters=16 loads) + bs1(t1) q0,q1 (4 loads);
  // VMW(4) completes t0; pre-read P1 operands.
  STB(bs0, 0, 0); STB(bs0, 1, 0); STB(bs0, 2, 0); STB(bs0, 3, 0);
  STA(as0, 0, 0); STA(as0, 1, 0); STA(as0, 2, 0); STA(as0, 3, 0);
  STB(bs1, 0, 1); STB(bs1, 1, 1);
  VMW(4); BAR();
  RD_LO(as0, c0); RD_B(bs0, b0, c0);

  for (int it = 0; it < NIT - 1; ++it) {
    const int t1 = 2 * it + 1, t2 = 2 * it + 2, t3 = 2 * it + 3;
    // P1: stage rest of t1 (6 quarters = 12 loads) [outstanding 16, all t1]
    STA(as1, 0, t1); STA(as1, 2, t1); STA(as1, 1, t1); STA(as1, 3, t1);
    STB(bs1, 2, t1); STB(bs1, 3, t1);
    RD_HI(as0, c0);
    MFMA_PH(MM_LO, b0); BAR();
    // P2
    RD_LO(as0, c1); RD_B(bs0, b1, c1);
    MFMA_PH(MM_HI, b0); BAR();
    // P3: bs0 dead after P2 -> stage t2 B (8 loads) [24]; VMW(8) completes
    //     oldest 16 = ALL t1. First t1 read P4.
    STB(bs0, 0, t2); STB(bs0, 1, t2); STB(bs0, 2, t2); STB(bs0, 3, t2);
    VMW(8);
    RD_HI(as0, c1);
    MFMA_PH(MM_LO, b1); BAR();
    // P4: as0 dead after P3 -> stage t2 A q0,q2 [12]
    STA(as0, 0, t2); STA(as0, 2, t2);
    RD_LO(as1, c0); RD_B(bs1, b0, c0);
    MFMA_PH(MM_HI, b1); BAR();
    // P5: stage t2 A q1,q3 [16]
    STA(as0, 1, t2); STA(as0, 3, t2);
    RD_HI(as1, c0);
    MFMA_PH(MM_LO, b0); BAR();
    // P6
    RD_LO(as1, c1); RD_B(bs1, b1, c1);
    MFMA_PH(MM_HI, b0); BAR();
    // P7: bs1 q0,q1 dead after P6 -> stage t3 (4 loads) [20]; VMW(4)
    //     completes oldest 16 = ALL t2. First t2 read P8.
    STB(bs1, 0, t3); STB(bs1, 1, t3);
    VMW(4);
    RD_HI(as1, c1);
    MFMA_PH(MM_LO, b1); BAR();
    // P8: read-ahead next-P1 operands (t2, guarded P7) [outstanding 4]
    RD_LO(as0, c0); RD_B(bs0, b0, c0);
    MFMA_PH(MM_HI, b1); BAR();
  }

  // ---- peeled last iteration ----
  {
    const int t1 = NT - 1;
    STA(as1, 0, t1); STA(as1, 2, t1); STA(as1, 1, t1); STA(as1, 3, t1);
    STB(bs1, 2, t1); STB(bs1, 3, t1);
    RD_HI(as0, c0);
    MFMA_PH(MM_LO, b0); BAR();
    RD_LO(as0, c1); RD_B(bs0, b1, c1);
    MFMA_PH(MM_HI, b0); BAR();
    VMW(0);
    RD_HI(as0, c1);
    MFMA_PH(MM_LO, b1); BAR();
    RD_LO(as1, c0); RD_B(bs1, b0, c0);
    MFMA_PH(MM_HI, b1); BAR();
    RD_HI(as1, c0);
    MFMA_PH(MM_LO, b0); BAR();
    RD_LO(as1, c1); RD_B(bs1, b1, c1);
    MFMA_PH(MM_HI, b0); BAR();
    RD_HI(as1, c1);
    MFMA_PH(MM_LO, b1); BAR();
    MFMA_PH(MM_HI, b1);
    BAR();  // LDS dead beyond this point (epilogue reuses SH)
  }

  if (MODE == 0) {
    const int r0 = wm * 128 + ((l >> 4) << 2);
    const int cc0 = wn * 128 + (l & 15);
#pragma unroll
    for (int mi = 0; mi < 8; ++mi) {
#pragma unroll
      for (int j = 0; j < 4; ++j) {
        long r = bm + r0 + mi * 16 + j;
#pragma unroll
        for (int ni = 0; ni < 8; ++ni) {
          long c = bn + cc0 + ni * 16;
          ((float*)Cout)[r * N + c] = acc[mi][ni][j] + bias[c];
        }
      }
    }
  } else {
    // stage C tile in SH [256][256] bf16 (swizzled), then coalesced stores
    const int sec = (int)(bn >> 10);
    const float kmul = (sec == 0) ? KSCALE : 1.0f;
    const int colBase = wn * 128 + (l & 15);
    const int rowBase = wm * 128 + ((l >> 4) << 2);
#pragma unroll
    for (int mi = 0; mi < 8; ++mi) {
#pragma unroll
      for (int j = 0; j < 4; ++j) {
        int row = rowBase + mi * 16 + j;
        int rsw = ((row >> 1) & 7) << 3;
#pragma unroll
        for (int ni = 0; ni < 8; ++ni) {
          int col = colBase + ni * 16;
          float v = (acc[mi][ni][j] + bias[bn + col]) * kmul;
          SH[row * 256 + (col ^ rsw)] = f2bf(v);
        }
      }
    }
    __syncthreads();
    u16* const dst = (sec == 0) ? q_out : (sec == 1) ? k_out : v_out;
    const int ebase = (int)(bn & 1023);
#pragma unroll
    for (int k = 0; k < 32; ++k) {
      int s5 = tid + 256 * k;
      int row = s5 >> 5;
      int col = (s5 & 31) * 8;
      ushort8 v = *(const ushort8*)(SH + row * 256 + (col ^ (((row >> 1) & 7) << 3)));
      long r = bm + row;
      int s = (int)(r >> 5), bb = (int)(r & 31);
      int e = ebase + col;
      int hh = e >> 6, d0 = e & 63;
      *(ushort8*)(dst + (((size_t)(bb * 16 + hh) * 512 + s) * 64) + d0) = v;
    }
  }
}

// ---------------- fused attention v6 (r12 state, frozen) ----------------
__global__ void __launch_bounds__(1024, 4) attn_v6(
    const u16* __restrict__ Q, const u16* __restrict__ K, const u16* __restrict__ V,
    const float* __restrict__ prefix_pool, const int* __restrict__ prompt_ids,
    const float* __restrict__ batch_weight, u16* __restrict__ attn_out) {
  constexpr int E = 1024, L = 16;
  const int h = blockIdx.x, b = blockIdx.y;
  const int tid = threadIdx.x;
  const int wid = tid >> 6, lane = tid & 63;
  const int fr = lane & 15, fkg = lane >> 4;

  __shared__ alignas(16) u16 Ks[2][64 * 64];
  __shared__ alignas(16) u16 VTs[2][64 * 64];
  __shared__ alignas(16) u16 Ps[16][16 * 64];
  __shared__ alignas(16) u16 pKs[L * 64];
  __shared__ alignas(16) u16 pVTs[64 * 32];

  const size_t bh = (size_t)(b * 16 + h);
  const u16* Kbase = K + bh * 512 * 64;
  const u16* Vbase = V + bh * 512 * 64;
  const u16* Qbase = Q + bh * 512 * 64;
  const int q0 = wid * 32;

  const bool isK = (tid < 512);
  const int st = isK ? tid : tid - 512;
  const int srow = st >> 3;
  const int scol = (st & 7) * 8;
  const u16* sbase = (isK ? Kbase : Vbase) + srow * 64 + scol;

  ushort8 stgA, stgB;
  stgA = *(const ushort8*)(sbase);

  const int pid = prompt_ids[b];
  const float* pk = prefix_pool + ((size_t)pid * 2 * L) * E + h * 64;
  const float* pv = pk + (size_t)L * E;
  if (tid < 256) {
    int ll = tid >> 4, d0 = (tid & 15) * 4;
    float4 v = *(const float4*)(pk + (size_t)ll * E + d0);
    u16 t4[4] = {f2bf(v.x), f2bf(v.y), f2bf(v.z), f2bf(v.w)};
#pragma unroll
    for (int i = 0; i < 4; ++i)
      pKs[(ll * 64 + d0 + i) ^ ((ll & 7) << 3)] = t4[i];
  } else if (tid < 512) {
    int t = tid - 256;
    int d = t >> 2, kv0 = (t & 3) * 8;
#pragma unroll
    for (int i = 0; i < 8; ++i) {
      int kv = kv0 + i;
      float v = (kv < L) ? pv[(size_t)kv * E + d] : 0.f;
      pVTs[d * 32 + kv] = f2bf(v);
    }
  }

  bf16x8 qf[2][2];
#pragma unroll
  for (int mt = 0; mt < 2; ++mt) {
    int qrow = q0 + mt * 16 + fr;
    qf[mt][0] = *(const bf16x8*)(Qbase + qrow * 64 + fkg * 8);
    qf[mt][1] = *(const bf16x8*)(Qbase + qrow * 64 + 32 + fkg * 8);
  }

  float m2[2] = {-3e38f, -3e38f}, lsum[2] = {0.f, 0.f};
  f32x4 oacc[2][4] = {};
  u16* const pw = Ps[wid];
  const int psw = (fr & 7) << 3;

#define STAGE_WRITE(STG, KSB, VTB)                                            \
  if (isK) {                                                                  \
    int e = (srow * 64 + scol) ^ ((srow & 7) << 3);                           \
    *(ushort8*)((KSB) + e) = STG;                                             \
  } else {                                                                    \
    _Pragma("unroll") for (int i = 0; i < 8; ++i) {                           \
      int d = scol + i;                                                       \
      (VTB)[(d * 64 + srow) ^ ((d & 7) << 3)] = STG[i];                       \
    }                                                                         \
  }

#define COMPUTE(KSB, VTB)                                                     \
  _Pragma("unroll") for (int mt = 0; mt < 2; ++mt) {                          \
    f32x4 sa[4];                                                              \
    _Pragma("unroll") for (int nt = 0; nt < 4; ++nt) {                        \
      int krow = nt * 16 + fr;                                                \
      int kb = krow * 64, swz = (krow & 7) << 3;                              \
      bf16x8 kf0 = *(const bf16x8*)((KSB) + ((kb + fkg * 8) ^ swz));          \
      bf16x8 kf1 = *(const bf16x8*)((KSB) + ((kb + 32 + fkg * 8) ^ swz));     \
      f32x4 z = {};                                                           \
      sa[nt] = mfma16(kf0, qf[mt][0], z);                                     \
      sa[nt] = mfma16(kf1, qf[mt][1], sa[nt]);                                \
    }                                                                         \
    float mx = sa[0][0];                                                      \
    _Pragma("unroll") for (int nt = 0; nt < 4; ++nt)                          \
      _Pragma("unroll") for (int j = 0; j < 4; ++j)                           \
        mx = fmaxf(mx, sa[nt][j]);                                            \
    mx = fmaxf(mx, __shfl_xor(mx, 16, 64));                                   \
    mx = fmaxf(mx, __shfl_xor(mx, 32, 64));                                   \
    if (!__all(mx <= m2[mt] + 8.0f)) {                                        \
      float mnew = fmaxf(m2[mt], mx);                                         \
      float al = fexp2(m2[mt] - mnew);                                        \
      lsum[mt] *= al;                                                         \
      _Pragma("unroll") for (int j = 0; j < 4; ++j) {                         \
        float alj = __shfl(al, fkg * 4 + j, 64);                              \
        _Pragma("unroll") for (int t = 0; t < 4; ++t) oacc[mt][t][j] *= alj;  \
      }                                                                       \
      m2[mt] = mnew;                                                          \
    }                                                                         \
    float sum = 0.f;                                                          \
    _Pragma("unroll") for (int nt = 0; nt < 4; ++nt)                          \
      _Pragma("unroll") for (int j = 0; j < 4; ++j) {                         \
        float p = fexp2(sa[nt][j] - m2[mt]);                                  \
        sa[nt][j] = p;                                                        \
        sum += p;                                                             \
      }                                                                       \
    sum += __shfl_xor(sum, 16, 64);                                           \
    sum += __shfl_xor(sum, 32, 64);                                           \
    lsum[mt] += sum;                                                          \
    _Pragma("unroll") for (int nt = 0; nt < 4; ++nt)                          \
      _Pragma("unroll") for (int i = 0; i < 2; ++i) {                         \
        unsigned int pack = (unsigned int)f2bf(sa[nt][2 * i]) |               \
                            ((unsigned int)f2bf(sa[nt][2 * i + 1]) << 16);    \
        int kv = nt * 16 + fkg * 4 + 2 * i;                                   \
        *(unsigned int*)(pw + fr * 64 + (kv ^ psw)) = pack;                   \
      }                                                                       \
    _Pragma("unroll") for (int kk = 0; kk < 2; ++kk) {                        \
      bf16x8 pa = *(const bf16x8*)(pw + fr * 64 + ((kk * 32 + fkg * 8) ^ psw)); \
      _Pragma("unroll") for (int t = 0; t < 4; ++t) {                         \
        int vd = t * 16 + fr;                                                 \
        bf16x8 vf = *(const bf16x8*)((VTB) + ((vd * 64 + kk * 32 + fkg * 8) ^ ((vd & 7) << 3))); \
        oacc[mt][t] = mfma16(pa, vf, oacc[mt][t]);                            \
      }                                                                       \
    }                                                                         \
  }

  STAGE_WRITE(stgA, Ks[0], VTs[0]);
  stgB = *(const ushort8*)(sbase + 4096);
  __syncthreads();

#define CHUNK(CUR, NXT, C)                                                    \
  {                                                                           \
    if ((C) < 7) STAGE_WRITE(CUR, Ks[((C) + 1) & 1], VTs[((C) + 1) & 1]);     \
    if ((C) < 6) NXT = *(const ushort8*)(sbase + ((C) + 2) * 4096);           \
    COMPUTE(Ks[(C) & 1], VTs[(C) & 1]);                                       \
    __syncthreads();                                                          \
  }

  CHUNK(stgB, stgA, 0);
  CHUNK(stgA, stgB, 1);
  CHUNK(stgB, stgA, 2);
  CHUNK(stgA, stgB, 3);
  CHUNK(stgB, stgA, 4);
  CHUNK(stgA, stgB, 5);
  CHUNK(stgB, stgA, 6);
  CHUNK(stgA, stgB, 7);

  const float bw = batch_weight[b];
#pragma unroll
  for (int mt = 0; mt < 2; ++mt) {
    f32x4 sp;
    {
      int swz = (fr & 7) << 3;
      bf16x8 a0 = *(const bf16x8*)(pKs + ((fr * 64 + fkg * 8) ^ swz));
      bf16x8 a1 = *(const bf16x8*)(pKs + ((fr * 64 + 32 + fkg * 8) ^ swz));
      f32x4 z = {};
      sp = mfma16(a0, qf[mt][0], z);
      sp = mfma16(a1, qf[mt][1], sp);
    }
    float mx = fmaxf(fmaxf(sp[0], sp[1]), fmaxf(sp[2], sp[3]));
    mx = fmaxf(mx, __shfl_xor(mx, 16, 64));
    mx = fmaxf(mx, __shfl_xor(mx, 32, 64));
    float psum = 0.f;
#pragma unroll
    for (int j = 0; j < 4; ++j) {
      float p = fexp2(sp[j] - mx);
      sp[j] = p;
      psum += p;
    }
    psum += __shfl_xor(psum, 16, 64);
    psum += __shfl_xor(psum, 32, 64);
#pragma unroll
    for (int i = 0; i < 2; ++i) {
      unsigned int pack = (unsigned int)f2bf(sp[2 * i]) |
                          ((unsigned int)f2bf(sp[2 * i + 1]) << 16);
      int kv = fkg * 4 + 2 * i;
      *(unsigned int*)(pw + fr * 64 + (kv ^ psw)) = pack;
      int kv2 = 16 + fkg * 4 + 2 * i;
      *(unsigned int*)(pw + fr * 64 + (kv2 ^ psw)) = 0u;
    }
    f32x4 op[4] = {};
    {
      bf16x8 pa = *(const bf16x8*)(pw + fr * 64 + ((fkg * 8) ^ psw));
#pragma unroll
      for (int t = 0; t < 4; ++t) {
        bf16x8 vf = *(const bf16x8*)(pVTs + (t * 16 + fr) * 32 + fkg * 8);
        op[t] = mfma16(pa, vf, op[t]);
      }
    }
#pragma unroll
    for (int j = 0; j < 4; ++j) {
      float lj = __shfl(lsum[mt], fkg * 4 + j, 64);
      float lpj = __shfl(psum, fkg * 4 + j, 64);
      int s = q0 + mt * 16 + fkg * 4 + j;
      size_t m = (size_t)s * 32 + b;
      float invl = 1.f / lj, invlp = 1.f / lpj;
#pragma unroll
      for (int t = 0; t < 4; ++t) {
        float v = oacc[mt][t][j] * invl + bw * op[t][j] * invlp;
        attn_out[m * E + h * 64 + t * 16 + fr] = f2bf(v);
      }
    }
  }
}

extern "C" void kernel_launch(void* const* d_in, const int* in_sizes, int n_in,
                              void* d_out, int out_size, void* d_ws, size_t ws_size,
                              hipStream_t stream) {
  const float* query = (const float*)d_in[0];
  const int* prompt_ids = (const int*)d_in[1];
  const float* batch_weight = (const float*)d_in[2];
  const float* in_proj_w = (const float*)d_in[3];
  const float* in_proj_b = (const float*)d_in[4];
  const float* out_proj_w = (const float*)d_in[5];
  const float* out_proj_b = (const float*)d_in[6];
  const float* prefix_pool = (const float*)d_in[7];
  float* out = (float*)d_out;

  u16* qbf = (u16*)d_ws;                      // 16384x1024
  u16* wqkv = qbf + (size_t)16384 * 1024;     // 3072x1024
  u16* wout = wqkv + (size_t)3072 * 1024;     // 1024x1024
  u16* qx = wout + (size_t)1024 * 1024;       // [b,h,s,d]
  u16* kx = qx + (size_t)32 * 16 * 512 * 64;
  u16* vx = kx + (size_t)32 * 16 * 512 * 64;
  u16* attnb = vx + (size_t)32 * 16 * 512 * 64;  // 16384x1024

  cvt_all<<<20480, 256, 0, stream>>>(query, in_proj_w, out_proj_w,
                                     qbf, wqkv, wout);

  gemm8p<2><<<dim3(64, 12), 256, 0, stream>>>(qbf, wqkv, in_proj_b, nullptr,
                                              qx, kx, vx, 16384, 3072, 1024);
  attn_v6<<<dim3(16, 32), 1024, 0, stream>>>(qx, kx, vx, prefix_pool, prompt_ids,
                                             batch_weight, attnb);
  gemm8p<0><<<dim3(64, 4), 256, 0, stream>>>(attnb, wout, out_proj_b, out,
                                             nullptr, nullptr, nullptr,
                                             16384, 1024, 1024);
}

// Round 14
// 238.429 us; speedup vs baseline: 1.2737x; 1.2737x over previous
//
#include <hip/hip_runtime.h>
#include <stdint.h>

typedef unsigned short u16;
typedef __attribute__((ext_vector_type(8))) __bf16 bf16x8;
typedef __attribute__((ext_vector_type(4))) float f32x4;
typedef __attribute__((ext_vector_type(8))) unsigned short ushort8;

__device__ __forceinline__ u16 f2bf(float f) {
  unsigned int u = __builtin_bit_cast(unsigned int, f);
  return (u16)((u + 0x7fffu + ((u >> 16) & 1u)) >> 16);
}

__device__ __forceinline__ float fexp2(float x) {
  float r;
  asm volatile("v_exp_f32 %0, %1" : "=v"(r) : "v"(x));
  return r;
}

__device__ __forceinline__ f32x4 mfma16(bf16x8 a, bf16x8 b, f32x4 c) {
  return __builtin_amdgcn_mfma_f32_16x16x32_bf16(a, b, c, 0, 0, 0);
}

__device__ __forceinline__ void gload_lds16(const void* g, void* l) {
  __builtin_amdgcn_global_load_lds((const __attribute__((address_space(1))) void*)g,
                                   (__attribute__((address_space(3))) void*)l,
                                   16, 0, 0);
}

#define KSCALE 0.18033688011112294f  /* 0.125 * log2(e) */

// ---------------- merged f32 -> bf16 convert (one launch) ----------------
__global__ void __launch_bounds__(256) cvt_all(
    const float* __restrict__ q, const float* __restrict__ w1,
    const float* __restrict__ w2, u16* __restrict__ qb,
    u16* __restrict__ w1b, u16* __restrict__ w2b) {
  int i = blockIdx.x * 256 + threadIdx.x;
  const float* src;
  u16* dst;
  int off;
  if (i < 4194304) {
    src = q; dst = qb; off = i;
  } else if (i < 4194304 + 786432) {
    src = w1; dst = w1b; off = i - 4194304;
  } else {
    src = w2; dst = w2b; off = i - 4980736;
  }
  float4 v = ((const float4*)src)[off];
  u16* d = dst + (size_t)off * 4;
  d[0] = f2bf(v.x); d[1] = f2bf(v.y); d[2] = f2bf(v.z); d[3] = f2bf(v.w);
}

// ================= 256x256 8-phase NT GEMM (r10/r12 verified state) ======
// Read-ahead pipelined: each phase issues ds_reads for the NEXT phase's
// MFMA, then runs MFMA on regs read last phase. Every vmcnt guard sits one
// phase BEFORE the first cross-wave read of the guarded tile (barrier chain
// makes the wait wave-global).
#define LDV(p) (*(const bf16x8*)(p))
#define RD_LO(AS, C) { aL[0]=LDV(AS+aRow+(C)); aL[1]=LDV(AS+aRow+1024+(C)); \
                       aL[2]=LDV(AS+aRow+2048+(C)); aL[3]=LDV(AS+aRow+3072+(C)); }
#define RD_HI(AS, C) { aH[0]=LDV(AS+aRow+4096+(C)); aH[1]=LDV(AS+aRow+5120+(C)); \
                       aH[2]=LDV(AS+aRow+6144+(C)); aH[3]=LDV(AS+aRow+7168+(C)); }
#define RD_B(BS, R, C) { R[0]=LDV(BS+bRow+(C)); R[1]=LDV(BS+bRow+1024+(C)); \
                         R[2]=LDV(BS+bRow+2048+(C)); R[3]=LDV(BS+bRow+3072+(C)); }
#define STA(DST, Q, T) gload_lds16(baseA + (Q)*K64 + (size_t)(T)*64, (DST) + (Q)*4096 + stDst)
#define STB(DST, Q, T) gload_lds16(baseB + (Q)*K64 + (size_t)(T)*64, (DST) + (Q)*4096 + stDst)
#define MM_LO(BB) { _Pragma("unroll") for (int mi=0;mi<4;++mi) \
                    _Pragma("unroll") for (int ni=0;ni<4;++ni) \
                      acc[mi][ni]=mfma16(aL[mi],(BB)[ni],acc[mi][ni]); }
#define MM_HI(BB) { _Pragma("unroll") for (int mi=0;mi<4;++mi) \
                    _Pragma("unroll") for (int ni=0;ni<4;++ni) \
                      acc[mi+4][ni]=mfma16(aH[mi],(BB)[ni],acc[mi+4][ni]); }
#define VMW(N) asm volatile("s_waitcnt vmcnt(" #N ")" ::: "memory")
#define BAR() __builtin_amdgcn_s_barrier()
#define PRIO1() __builtin_amdgcn_s_setprio(1)
#define PRIO0() __builtin_amdgcn_s_setprio(0)
#define MFMA_PH(MM, BB) { PRIO1(); MM(BB); PRIO0(); }

template <int MODE>
__global__ void __launch_bounds__(512, 2) gemm8p(
    const u16* __restrict__ A, const u16* __restrict__ B,
    const float* __restrict__ bias, void* __restrict__ Cout,
    u16* __restrict__ q_out, u16* __restrict__ k_out, u16* __restrict__ v_out,
    int M, int N, int K) {
  __shared__ alignas(16) u16 SH[65536];

  const int tid = threadIdx.x;
  const int w = tid >> 6, l = tid & 63;
  const int wm = w >> 2, wn = w & 3;
  const long bm = (long)blockIdx.x * 256;
  const long bn = (long)blockIdx.y * 256;
  const int NT = K >> 6;
  const int NIT = NT >> 1;

  const int srow = w * 8 + (l >> 3);
  const int schk = ((l & 7) ^ (l >> 3)) * 8;
  const u16* baseA = A + (bm + srow) * (size_t)K + schk;
  const u16* baseB = B + (bn + srow) * (size_t)K + schk;
  const size_t K64 = (size_t)K * 64;
  const int stDst = w * 512;

  u16* const as0 = SH;
  u16* const as1 = SH + 16384;
  u16* const bs0 = SH + 32768;
  u16* const bs1 = SH + 49152;

  const int fr = l & 15, fkg = l >> 4;
  const int sw = (fr & 7) << 3;
  const int c0 = (fkg * 8) ^ sw;
  const int c1 = (32 + fkg * 8) ^ sw;
  const int aRow = (wm * 128 + fr) * 64;
  const int bRow = (wn * 64 + fr) * 64;

  f32x4 acc[8][4] = {};
  bf16x8 aL[4], aH[4], b0[4], b1[4];

  STB(bs0, 0, 0); STB(bs0, 1, 0); STB(bs0, 2, 0); STB(bs0, 3, 0);
  STA(as0, 0, 0); STA(as0, 1, 0); STA(as0, 2, 0); STA(as0, 3, 0);
  STB(bs1, 0, 1); STB(bs1, 1, 1);
  VMW(2); BAR();
  RD_LO(as0, c0); RD_B(bs0, b0, c0);

  for (int it = 0; it < NIT - 1; ++it) {
    const int t1 = 2 * it + 1, t2 = 2 * it + 2, t3 = 2 * it + 3;
    STA(as1, 0, t1); STA(as1, 2, t1); STA(as1, 1, t1); STA(as1, 3, t1);
    STB(bs1, 2, t1); STB(bs1, 3, t1);
    RD_HI(as0, c0);
    MFMA_PH(MM_LO, b0); BAR();
    RD_LO(as0, c1); RD_B(bs0, b1, c1);
    MFMA_PH(MM_HI, b0); BAR();
    STB(bs0, 0, t2); STB(bs0, 1, t2); STB(bs0, 2, t2); STB(bs0, 3, t2);
    VMW(4);
    RD_HI(as0, c1);
    MFMA_PH(MM_LO, b1); BAR();
    STA(as0, 0, t2); STA(as0, 2, t2);
    RD_LO(as1, c0); RD_B(bs1, b0, c0);
    MFMA_PH(MM_HI, b1); BAR();
    STA(as0, 1, t2); STA(as0, 3, t2);
    RD_HI(as1, c0);
    MFMA_PH(MM_LO, b0); BAR();
    RD_LO(as1, c1); RD_B(bs1, b1, c1);
    MFMA_PH(MM_HI, b0); BAR();
    STB(bs1, 0, t3); STB(bs1, 1, t3);
    VMW(2);
    RD_HI(as1, c1);
    MFMA_PH(MM_LO, b1); BAR();
    RD_LO(as0, c0); RD_B(bs0, b0, c0);
    MFMA_PH(MM_HI, b1); BAR();
  }
  {
    const int t1 = NT - 1;
    STA(as1, 0, t1); STA(as1, 2, t1); STA(as1, 1, t1); STA(as1, 3, t1);
    STB(bs1, 2, t1); STB(bs1, 3, t1);
    RD_HI(as0, c0);
    MFMA_PH(MM_LO, b0); BAR();
    RD_LO(as0, c1); RD_B(bs0, b1, c1);
    MFMA_PH(MM_HI, b0); BAR();
    VMW(0);
    RD_HI(as0, c1);
    MFMA_PH(MM_LO, b1); BAR();
    RD_LO(as1, c0); RD_B(bs1, b0, c0);
    MFMA_PH(MM_HI, b1); BAR();
    RD_HI(as1, c0);
    MFMA_PH(MM_LO, b0); BAR();
    RD_LO(as1, c1); RD_B(bs1, b1, c1);
    MFMA_PH(MM_HI, b0); BAR();
    RD_HI(as1, c1);
    MFMA_PH(MM_LO, b1); BAR();
    MFMA_PH(MM_HI, b1);
    BAR();
  }

  if (MODE == 0) {
    const int r0 = wm * 128 + ((l >> 4) << 2);
    const int cc0 = wn * 64 + (l & 15);
#pragma unroll
    for (int mi = 0; mi < 8; ++mi) {
#pragma unroll
      for (int j = 0; j < 4; ++j) {
        long r = bm + r0 + mi * 16 + j;
#pragma unroll
        for (int ni = 0; ni < 4; ++ni) {
          long c = bn + cc0 + ni * 16;
          ((float*)Cout)[r * N + c] = acc[mi][ni][j] + bias[c];
        }
      }
    }
  } else {
    const int sec = (int)(bn >> 10);
    const float kmul = (sec == 0) ? KSCALE : 1.0f;
    const int colBase = wn * 64 + (l & 15);
    const int rowBase = wm * 128 + ((l >> 4) << 2);
#pragma unroll
    for (int mi = 0; mi < 8; ++mi) {
#pragma unroll
      for (int j = 0; j < 4; ++j) {
        int row = rowBase + mi * 16 + j;
        int rsw = ((row >> 1) & 7) << 3;
#pragma unroll
        for (int ni = 0; ni < 4; ++ni) {
          int col = colBase + ni * 16;
          float v = (acc[mi][ni][j] + bias[bn + col]) * kmul;
          SH[row * 256 + (col ^ rsw)] = f2bf(v);
        }
      }
    }
    __syncthreads();
    u16* const dst = (sec == 0) ? q_out : (sec == 1) ? k_out : v_out;
    const int ebase = (int)(bn & 1023);
#pragma unroll
    for (int k = 0; k < 16; ++k) {
      int s5 = tid + 512 * k;
      int row = s5 >> 5;
      int col = (s5 & 31) * 8;
      ushort8 v = *(const ushort8*)(SH + row * 256 + (col ^ (((row >> 1) & 7) << 3)));
      long r = bm + row;
      int s = (int)(r >> 5), bb = (int)(r & 31);
      int e = ebase + col;
      int hh = e >> 6, d0 = e & 63;
      *(ushort8*)(dst + (((size_t)(bb * 16 + hh) * 512 + s) * 64) + d0) = v;
    }
  }
}

// ---------------- fused attention v6 (r12 verified state) ----------------
__global__ void __launch_bounds__(1024, 4) attn_v6(
    const u16* __restrict__ Q, const u16* __restrict__ K, const u16* __restrict__ V,
    const float* __restrict__ prefix_pool, const int* __restrict__ prompt_ids,
    const float* __restrict__ batch_weight, u16* __restrict__ attn_out) {
  constexpr int E = 1024, L = 16;
  const int h = blockIdx.x, b = blockIdx.y;
  const int tid = threadIdx.x;
  const int wid = tid >> 6, lane = tid & 63;
  const int fr = lane & 15, fkg = lane >> 4;

  __shared__ alignas(16) u16 Ks[2][64 * 64];
  __shared__ alignas(16) u16 VTs[2][64 * 64];
  __shared__ alignas(16) u16 Ps[16][16 * 64];
  __shared__ alignas(16) u16 pKs[L * 64];
  __shared__ alignas(16) u16 pVTs[64 * 32];

  const size_t bh = (size_t)(b * 16 + h);
  const u16* Kbase = K + bh * 512 * 64;
  const u16* Vbase = V + bh * 512 * 64;
  const u16* Qbase = Q + bh * 512 * 64;
  const int q0 = wid * 32;

  const bool isK = (tid < 512);
  const int st = isK ? tid : tid - 512;
  const int srow = st >> 3;
  const int scol = (st & 7) * 8;
  const u16* sbase = (isK ? Kbase : Vbase) + srow * 64 + scol;

  ushort8 stgA, stgB;
  stgA = *(const ushort8*)(sbase);

  const int pid = prompt_ids[b];
  const float* pk = prefix_pool + ((size_t)pid * 2 * L) * E + h * 64;
  const float* pv = pk + (size_t)L * E;
  if (tid < 256) {
    int ll = tid >> 4, d0 = (tid & 15) * 4;
    float4 v = *(const float4*)(pk + (size_t)ll * E + d0);
    u16 t4[4] = {f2bf(v.x), f2bf(v.y), f2bf(v.z), f2bf(v.w)};
#pragma unroll
    for (int i = 0; i < 4; ++i)
      pKs[(ll * 64 + d0 + i) ^ ((ll & 7) << 3)] = t4[i];
  } else if (tid < 512) {
    int t = tid - 256;
    int d = t >> 2, kv0 = (t & 3) * 8;
#pragma unroll
    for (int i = 0; i < 8; ++i) {
      int kv = kv0 + i;
      float v = (kv < L) ? pv[(size_t)kv * E + d] : 0.f;
      pVTs[d * 32 + kv] = f2bf(v);
    }
  }

  bf16x8 qf[2][2];
#pragma unroll
  for (int mt = 0; mt < 2; ++mt) {
    int qrow = q0 + mt * 16 + fr;
    qf[mt][0] = *(const bf16x8*)(Qbase + qrow * 64 + fkg * 8);
    qf[mt][1] = *(const bf16x8*)(Qbase + qrow * 64 + 32 + fkg * 8);
  }

  float m2[2] = {-3e38f, -3e38f}, lsum[2] = {0.f, 0.f};
  f32x4 oacc[2][4] = {};
  u16* const pw = Ps[wid];
  const int psw = (fr & 7) << 3;

#define STAGE_WRITE(STG, KSB, VTB)                                            \
  if (isK) {                                                                  \
    int e = (srow * 64 + scol) ^ ((srow & 7) << 3);                           \
    *(ushort8*)((KSB) + e) = STG;                                             \
  } else {                                                                    \
    _Pragma("unroll") for (int i = 0; i < 8; ++i) {                           \
      int d = scol + i;                                                       \
      (VTB)[(d * 64 + srow) ^ ((d & 7) << 3)] = STG[i];                       \
    }                                                                         \
  }

#define COMPUTE(KSB, VTB)                                                     \
  _Pragma("unroll") for (int mt = 0; mt < 2; ++mt) {                          \
    f32x4 sa[4];                                                              \
    _Pragma("unroll") for (int nt = 0; nt < 4; ++nt) {                        \
      int krow = nt * 16 + fr;                                                \
      int kb = krow * 64, swz = (krow & 7) << 3;                              \
      bf16x8 kf0 = *(const bf16x8*)((KSB) + ((kb + fkg * 8) ^ swz));          \
      bf16x8 kf1 = *(const bf16x8*)((KSB) + ((kb + 32 + fkg * 8) ^ swz));     \
      f32x4 z = {};                                                           \
      sa[nt] = mfma16(kf0, qf[mt][0], z);                                     \
      sa[nt] = mfma16(kf1, qf[mt][1], sa[nt]);                                \
    }                                                                         \
    float mx = sa[0][0];                                                      \
    _Pragma("unroll") for (int nt = 0; nt < 4; ++nt)                          \
      _Pragma("unroll") for (int j = 0; j < 4; ++j)                           \
        mx = fmaxf(mx, sa[nt][j]);                                            \
    mx = fmaxf(mx, __shfl_xor(mx, 16, 64));                                   \
    mx = fmaxf(mx, __shfl_xor(mx, 32, 64));                                   \
    if (!__all(mx <= m2[mt] + 8.0f)) {                                        \
      float mnew = fmaxf(m2[mt], mx);                                         \
      float al = fexp2(m2[mt] - mnew);                                        \
      lsum[mt] *= al;                                                         \
      _Pragma("unroll") for (int j = 0; j < 4; ++j) {                         \
        float alj = __shfl(al, fkg * 4 + j, 64);                              \
        _Pragma("unroll") for (int t = 0; t < 4; ++t) oacc[mt][t][j] *= alj;  \
      }                                                                       \
      m2[mt] = mnew;                                                          \
    }                                                                         \
    float sum = 0.f;                                                          \
    _Pragma("unroll") for (int nt = 0; nt < 4; ++nt)                          \
      _Pragma("unroll") for (int j = 0; j < 4; ++j) {                         \
        float p = fexp2(sa[nt][j] - m2[mt]);                                  \
        sa[nt][j] = p;                                                        \
        sum += p;                                                             \
      }                                                                       \
    sum += __shfl_xor(sum, 16, 64);                                           \
    sum += __shfl_xor(sum, 32, 64);                                           \
    lsum[mt] += sum;                                                          \
    _Pragma("unroll") for (int nt = 0; nt < 4; ++nt)                          \
      _Pragma("unroll") for (int i = 0; i < 2; ++i) {                         \
        unsigned int pack = (unsigned int)f2bf(sa[nt][2 * i]) |               \
                            ((unsigned int)f2bf(sa[nt][2 * i + 1]) << 16);    \
        int kv = nt * 16 + fkg * 4 + 2 * i;                                   \
        *(unsigned int*)(pw + fr * 64 + (kv ^ psw)) = pack;                   \
      }                                                                       \
    _Pragma("unroll") for (int kk = 0; kk < 2; ++kk) {                        \
      bf16x8 pa = *(const bf16x8*)(pw + fr * 64 + ((kk * 32 + fkg * 8) ^ psw)); \
      _Pragma("unroll") for (int t = 0; t < 4; ++t) {                         \
        int vd = t * 16 + fr;                                                 \
        bf16x8 vf = *(const bf16x8*)((VTB) + ((vd * 64 + kk * 32 + fkg * 8) ^ ((vd & 7) << 3))); \
        oacc[mt][t] = mfma16(pa, vf, oacc[mt][t]);                            \
      }                                                                       \
    }                                                                         \
  }

  STAGE_WRITE(stgA, Ks[0], VTs[0]);
  stgB = *(const ushort8*)(sbase + 4096);
  __syncthreads();

#define CHUNK(CUR, NXT, C)                                                    \
  {                                                                           \
    if ((C) < 7) STAGE_WRITE(CUR, Ks[((C) + 1) & 1], VTs[((C) + 1) & 1]);     \
    if ((C) < 6) NXT = *(const ushort8*)(sbase + ((C) + 2) * 4096);           \
    COMPUTE(Ks[(C) & 1], VTs[(C) & 1]);                                       \
    __syncthreads();                                                          \
  }

  CHUNK(stgB, stgA, 0);
  CHUNK(stgA, stgB, 1);
  CHUNK(stgB, stgA, 2);
  CHUNK(stgA, stgB, 3);
  CHUNK(stgB, stgA, 4);
  CHUNK(stgA, stgB, 5);
  CHUNK(stgB, stgA, 6);
  CHUNK(stgA, stgB, 7);

  const float bw = batch_weight[b];
#pragma unroll
  for (int mt = 0; mt < 2; ++mt) {
    f32x4 sp;
    {
      int swz = (fr & 7) << 3;
      bf16x8 a0 = *(const bf16x8*)(pKs + ((fr * 64 + fkg * 8) ^ swz));
      bf16x8 a1 = *(const bf16x8*)(pKs + ((fr * 64 + 32 + fkg * 8) ^ swz));
      f32x4 z = {};
      sp = mfma16(a0, qf[mt][0], z);
      sp = mfma16(a1, qf[mt][1], sp);
    }
    float mx = fmaxf(fmaxf(sp[0], sp[1]), fmaxf(sp[2], sp[3]));
    mx = fmaxf(mx, __shfl_xor(mx, 16, 64));
    mx = fmaxf(mx, __shfl_xor(mx, 32, 64));
    float psum = 0.f;
#pragma unroll
    for (int j = 0; j < 4; ++j) {
      float p = fexp2(sp[j] - mx);
      sp[j] = p;
      psum += p;
    }
    psum += __shfl_xor(psum, 16, 64);
    psum += __shfl_xor(psum, 32, 64);
#pragma unroll
    for (int i = 0; i < 2; ++i) {
      unsigned int pack = (unsigned int)f2bf(sp[2 * i]) |
                          ((unsigned int)f2bf(sp[2 * i + 1]) << 16);
      int kv = fkg * 4 + 2 * i;
      *(unsigned int*)(pw + fr * 64 + (kv ^ psw)) = pack;
      int kv2 = 16 + fkg * 4 + 2 * i;
      *(unsigned int*)(pw + fr * 64 + (kv2 ^ psw)) = 0u;
    }
    f32x4 op[4] = {};
    {
      bf16x8 pa = *(const bf16x8*)(pw + fr * 64 + ((fkg * 8) ^ psw));
#pragma unroll
      for (int t = 0; t < 4; ++t) {
        bf16x8 vf = *(const bf16x8*)(pVTs + (t * 16 + fr) * 32 + fkg * 8);
        op[t] = mfma16(pa, vf, op[t]);
      }
    }
#pragma unroll
    for (int j = 0; j < 4; ++j) {
      float lj = __shfl(lsum[mt], fkg * 4 + j, 64);
      float lpj = __shfl(psum, fkg * 4 + j, 64);
      int s = q0 + mt * 16 + fkg * 4 + j;
      size_t m = (size_t)s * 32 + b;
      float invl = 1.f / lj, invlp = 1.f / lpj;
#pragma unroll
      for (int t = 0; t < 4; ++t) {
        float v = oacc[mt][t][j] * invl + bw * op[t][j] * invlp;
        attn_out[m * E + h * 64 + t * 16 + fr] = f2bf(v);
      }
    }
  }
}

extern "C" void kernel_launch(void* const* d_in, const int* in_sizes, int n_in,
                              void* d_out, int out_size, void* d_ws, size_t ws_size,
                              hipStream_t stream) {
  const float* query = (const float*)d_in[0];
  const int* prompt_ids = (const int*)d_in[1];
  const float* batch_weight = (const float*)d_in[2];
  const float* in_proj_w = (const float*)d_in[3];
  const float* in_proj_b = (const float*)d_in[4];
  const float* out_proj_w = (const float*)d_in[5];
  const float* out_proj_b = (const float*)d_in[6];
  const float* prefix_pool = (const float*)d_in[7];
  float* out = (float*)d_out;

  u16* qbf = (u16*)d_ws;                      // 16384x1024
  u16* wqkv = qbf + (size_t)16384 * 1024;     // 3072x1024
  u16* wout = wqkv + (size_t)3072 * 1024;     // 1024x1024
  u16* qx = wout + (size_t)1024 * 1024;       // [b,h,s,d]
  u16* kx = qx + (size_t)32 * 16 * 512 * 64;
  u16* vx = kx + (size_t)32 * 16 * 512 * 64;
  u16* attnb = vx + (size_t)32 * 16 * 512 * 64;  // 16384x1024

  cvt_all<<<20480, 256, 0, stream>>>(query, in_proj_w, out_proj_w,
                                     qbf, wqkv, wout);

  gemm8p<2><<<dim3(64, 12), 512, 0, stream>>>(qbf, wqkv, in_proj_b, nullptr,
                                              qx, kx, vx, 16384, 3072, 1024);
  attn_v6<<<dim3(16, 32), 1024, 0, stream>>>(qx, kx, vx, prefix_pool, prompt_ids,
                                             batch_weight, attnb);
  gemm8p<0><<<dim3(64, 4), 512, 0, stream>>>(attnb, wout, out_proj_b, out,
                                             nullptr, nullptr, nullptr,
                                             16384, 1024, 1024);
}